// Round 1
// baseline (1402.520 us; speedup 1.0000x reference)
//
#include <hip/hip_runtime.h>

#define N_NODES 50000
#define N_EDGES 500000
#define IN_C 128
#define HID_C 128
#define OUT_C 64

// ---------------- degree / dinv ----------------

__global__ void deg_kernel(const int* __restrict__ dst, float* __restrict__ deg) {
    int e = blockIdx.x * blockDim.x + threadIdx.x;
    if (e < N_EDGES) atomicAdd(&deg[dst[e]], 1.0f);
}

__global__ void dinv_kernel(float* __restrict__ deg) {
    int i = blockIdx.x * blockDim.x + threadIdx.x;
    if (i < N_NODES) deg[i] = rsqrtf(deg[i] + 1.0f);
}

// ---------------- GEMM: H[n, NOUT] = X[n, 128] @ W[128, NOUT] ----------------

template <int NOUT>
__global__ __launch_bounds__(256) void gemm_kernel(const float* __restrict__ X,
                                                   const float* __restrict__ W,
                                                   float* __restrict__ H, int nrows) {
    constexpr int ROWS = 32;
    constexpr int GROUPS = 256 / NOUT;   // 2 for NOUT=128, 4 for NOUT=64
    constexpr int RPT = ROWS / GROUPS;   // 16 or 8 rows per thread

    __shared__ float4 Xl[ROWS][32];      // 32 rows x 128 floats

    const int tx = threadIdx.x % NOUT;
    const int ty = threadIdx.x / NOUT;
    const int row0 = blockIdx.x * ROWS;

    // cooperative load of X tile (float4-coalesced)
    for (int i = threadIdx.x; i < ROWS * 32; i += 256) {
        int r = i / 32, c = i % 32;
        int gr = row0 + r;
        Xl[r][c] = (gr < nrows) ? ((const float4*)X)[gr * 32 + c]
                                : make_float4(0.f, 0.f, 0.f, 0.f);
    }
    __syncthreads();

    float acc[RPT];
#pragma unroll
    for (int r = 0; r < RPT; r++) acc[r] = 0.f;

#pragma unroll 4
    for (int k4 = 0; k4 < 32; k4++) {
        const float w0 = W[(4 * k4 + 0) * NOUT + tx];
        const float w1 = W[(4 * k4 + 1) * NOUT + tx];
        const float w2 = W[(4 * k4 + 2) * NOUT + tx];
        const float w3 = W[(4 * k4 + 3) * NOUT + tx];
#pragma unroll
        for (int r = 0; r < RPT; r++) {
            float4 xv = Xl[ty * RPT + r][k4];  // broadcast across lanes (same addr)
            acc[r] = fmaf(xv.x, w0, acc[r]);
            acc[r] = fmaf(xv.y, w1, acc[r]);
            acc[r] = fmaf(xv.z, w2, acc[r]);
            acc[r] = fmaf(xv.w, w3, acc[r]);
        }
    }

#pragma unroll
    for (int r = 0; r < RPT; r++) {
        int gr = row0 + ty * RPT + r;
        if (gr < nrows) H[gr * NOUT + tx] = acc[r];
    }
}

// ---------------- edge scatter: agg[dst] += dinv[src]*dinv[dst] * H[src] ----------------

template <int NOUT>
__global__ __launch_bounds__(256) void scatter_kernel(const int* __restrict__ src,
                                                      const int* __restrict__ dst,
                                                      const float* __restrict__ dinv,
                                                      const float* __restrict__ H,
                                                      float* __restrict__ agg) {
    constexpr int LPE = NOUT / 4;  // lanes per edge (float4 per lane)
    long long tid = (long long)blockIdx.x * blockDim.x + threadIdx.x;
    int e = (int)(tid / LPE);
    int c = (int)(tid % LPE);
    if (e >= N_EDGES) return;
    int s = src[e];
    int d = dst[e];
    float coef = dinv[s] * dinv[d];
    float4 hv = ((const float4*)H)[(long long)s * LPE + c];
    float* out = &agg[(long long)d * NOUT + c * 4];
    atomicAdd(out + 0, coef * hv.x);
    atomicAdd(out + 1, coef * hv.y);
    atomicAdd(out + 2, coef * hv.z);
    atomicAdd(out + 3, coef * hv.w);
}

// ---------------- epilogues ----------------

// h2 = relu(agg + dinv^2 * h1 + b)   (in place over agg)
__global__ void epilogue1_kernel(const float* __restrict__ h1,
                                 const float* __restrict__ dinv,
                                 const float* __restrict__ b,
                                 float* __restrict__ agg) {
    int i = blockIdx.x * blockDim.x + threadIdx.x;
    if (i >= N_NODES * HID_C) return;
    int node = i >> 7;
    int c = i & 127;
    float di = dinv[node];
    float v = agg[i] + di * di * h1[i] + b[c];
    agg[i] = fmaxf(v, 0.f);
}

// out = out + dinv^2 * h3 + b   (out already holds scatter result)
__global__ void epilogue2_kernel(const float* __restrict__ h3,
                                 const float* __restrict__ dinv,
                                 const float* __restrict__ b,
                                 float* __restrict__ out) {
    int i = blockIdx.x * blockDim.x + threadIdx.x;
    if (i >= N_NODES * OUT_C) return;
    int node = i >> 6;
    int c = i & 63;
    float di = dinv[node];
    out[i] = out[i] + di * di * h3[i] + b[c];
}

// ---------------- launch ----------------

extern "C" void kernel_launch(void* const* d_in, const int* in_sizes, int n_in,
                              void* d_out, int out_size, void* d_ws, size_t ws_size,
                              hipStream_t stream) {
    const float* x  = (const float*)d_in[0];
    const int*   ei = (const int*)d_in[1];   // [2, N_EDGES] int32
    const float* W1 = (const float*)d_in[2];
    const float* b1 = (const float*)d_in[3];
    const float* W2 = (const float*)d_in[4];
    const float* b2 = (const float*)d_in[5];

    const int* src = ei;
    const int* dst = ei + N_EDGES;

    float* ws = (float*)d_ws;
    float* dinv = ws;                          // 50000 floats (deg then dinv, in place)
    float* h1   = ws + N_NODES;                // 50000*128
    float* agg1 = h1 + (size_t)N_NODES * HID_C; // 50000*128 (becomes h2 in place)
    float* h3   = h1;                           // reuse h1 region: 50000*64

    float* out = (float*)d_out;

    // 1) degree counting -> dinv
    hipMemsetAsync(dinv, 0, N_NODES * sizeof(float), stream);
    deg_kernel<<<(N_EDGES + 255) / 256, 256, 0, stream>>>(dst, dinv);
    dinv_kernel<<<(N_NODES + 255) / 256, 256, 0, stream>>>(dinv);

    // 2) h1 = x @ W1
    gemm_kernel<HID_C><<<(N_NODES + 31) / 32, 256, 0, stream>>>(x, W1, h1, N_NODES);

    // 3) agg1 = scatter(coef * h1[src] -> dst)
    hipMemsetAsync(agg1, 0, (size_t)N_NODES * HID_C * sizeof(float), stream);
    {
        long long total = (long long)N_EDGES * (HID_C / 4);
        scatter_kernel<HID_C><<<(int)((total + 255) / 256), 256, 0, stream>>>(src, dst, dinv, h1, agg1);
    }

    // 4) h2 = relu(agg1 + dinv^2*h1 + b1)  (in place in agg1)
    epilogue1_kernel<<<(N_NODES * HID_C + 255) / 256, 256, 0, stream>>>(h1, dinv, b1, agg1);

    // 5) h3 = h2 @ W2
    gemm_kernel<OUT_C><<<(N_NODES + 31) / 32, 256, 0, stream>>>(agg1, W2, h3, N_NODES);

    // 6) out = scatter(coef * h3[src] -> dst)
    hipMemsetAsync(out, 0, (size_t)N_NODES * OUT_C * sizeof(float), stream);
    {
        long long total = (long long)N_EDGES * (OUT_C / 4);
        scatter_kernel<OUT_C><<<(int)((total + 255) / 256), 256, 0, stream>>>(src, dst, dinv, h3, out);
    }

    // 7) out += dinv^2*h3 + b2
    epilogue2_kernel<<<(N_NODES * OUT_C + 255) / 256, 256, 0, stream>>>(h3, dinv, b2, out);
}

// Round 2
// 345.179 us; speedup vs baseline: 4.0632x; 4.0632x over previous
//
#include <hip/hip_runtime.h>

#define N_NODES 50000
#define N_EDGES 500000
#define IN_C 128
#define HID_C 128
#define OUT_C 64

// ---------------- CSR build ----------------

__global__ void deg_kernel(const int* __restrict__ dst, int* __restrict__ degi) {
    int e = blockIdx.x * blockDim.x + threadIdx.x;
    if (e < N_EDGES) atomicAdd(&degi[dst[e]], 1);
}

// Single-block exclusive scan over 50000 degrees -> rowptr[0..50000], plus dinv.
__global__ __launch_bounds__(256) void scan_kernel(const int* __restrict__ degi,
                                                   int* __restrict__ rowptr,
                                                   float* __restrict__ dinv) {
    __shared__ int partial[256];
    const int T = 256;
    const int t = threadIdx.x;
    const int chunk = (N_NODES + T - 1) / T;  // 196
    const int start = t * chunk;
    const int end = min(start + chunk, N_NODES);

    int s = 0;
    for (int i = start; i < end; i++) s += degi[i];
    partial[t] = s;
    __syncthreads();

    // Hillis-Steele inclusive scan of partials
    for (int off = 1; off < T; off <<= 1) {
        int tmp = (t >= off) ? partial[t - off] : 0;
        __syncthreads();
        partial[t] += tmp;
        __syncthreads();
    }

    int run = partial[t] - s;  // exclusive prefix for this thread's chunk
    for (int i = start; i < end; i++) {
        rowptr[i] = run;
        run += degi[i];
        dinv[i] = rsqrtf((float)degi[i] + 1.0f);
    }
    if (end == N_NODES && start < N_NODES) rowptr[N_NODES] = run;
    if (t == T - 1) rowptr[N_NODES] = run;  // covers exact-fit case
}

__global__ void fill_kernel(const int* __restrict__ src, const int* __restrict__ dst,
                            int* __restrict__ cursor, int* __restrict__ csr_src) {
    int e = blockIdx.x * blockDim.x + threadIdx.x;
    if (e < N_EDGES) {
        int d = dst[e];
        int pos = atomicAdd(&cursor[d], 1);
        csr_src[pos] = src[e];
    }
}

// ---------------- GEMM: H[n, NOUT] = X[n, 128] @ W[128, NOUT] ----------------

template <int NOUT>
__global__ __launch_bounds__(256) void gemm_kernel(const float* __restrict__ X,
                                                   const float* __restrict__ W,
                                                   float* __restrict__ H, int nrows) {
    constexpr int ROWS = 32;
    constexpr int GROUPS = 256 / NOUT;   // 2 for NOUT=128, 4 for NOUT=64
    constexpr int RPT = ROWS / GROUPS;   // 16 or 8 rows per thread

    __shared__ float4 Xl[ROWS][32];      // 32 rows x 128 floats

    const int tx = threadIdx.x % NOUT;
    const int ty = threadIdx.x / NOUT;
    const int row0 = blockIdx.x * ROWS;

    for (int i = threadIdx.x; i < ROWS * 32; i += 256) {
        int r = i / 32, c = i % 32;
        int gr = row0 + r;
        Xl[r][c] = (gr < nrows) ? ((const float4*)X)[gr * 32 + c]
                                : make_float4(0.f, 0.f, 0.f, 0.f);
    }
    __syncthreads();

    float acc[RPT];
#pragma unroll
    for (int r = 0; r < RPT; r++) acc[r] = 0.f;

#pragma unroll 4
    for (int k4 = 0; k4 < 32; k4++) {
        const float w0 = W[(4 * k4 + 0) * NOUT + tx];
        const float w1 = W[(4 * k4 + 1) * NOUT + tx];
        const float w2 = W[(4 * k4 + 2) * NOUT + tx];
        const float w3 = W[(4 * k4 + 3) * NOUT + tx];
#pragma unroll
        for (int r = 0; r < RPT; r++) {
            float4 xv = Xl[ty * RPT + r][k4];
            acc[r] = fmaf(xv.x, w0, acc[r]);
            acc[r] = fmaf(xv.y, w1, acc[r]);
            acc[r] = fmaf(xv.z, w2, acc[r]);
            acc[r] = fmaf(xv.w, w3, acc[r]);
        }
    }

#pragma unroll
    for (int r = 0; r < RPT; r++) {
        int gr = row0 + ty * RPT + r;
        if (gr < nrows) H[gr * NOUT + tx] = acc[r];
    }
}

// ---------------- fused aggregation + epilogue ----------------
// out[n][c] = (relu?)( dinv[n]^2 * H[n][c] + b[c] + sum_{s in nbrs(n)} dinv[n]*dinv[s]*H[s][c] )

template <int NOUT, bool RELU>
__global__ __launch_bounds__(256) void agg_kernel(const int* __restrict__ rowptr,
                                                  const int* __restrict__ csr_src,
                                                  const float* __restrict__ dinv,
                                                  const float* __restrict__ H,
                                                  const float* __restrict__ b,
                                                  float* __restrict__ out) {
    constexpr int NPB = 256 / NOUT;  // nodes per block: 2 (NOUT=128) or 4 (NOUT=64)
    const int node = blockIdx.x * NPB + threadIdx.x / NOUT;
    const int c = threadIdx.x % NOUT;
    if (node >= N_NODES) return;

    const float dn = dinv[node];
    float acc = dn * dn * H[(size_t)node * NOUT + c] + b[c];

    int e = rowptr[node];
    const int end = rowptr[node + 1];

    // unroll-by-2 to overlap the two gather loads
    for (; e + 1 < end; e += 2) {
        int s0 = csr_src[e];
        int s1 = csr_src[e + 1];
        float h0 = H[(size_t)s0 * NOUT + c];
        float h1v = H[(size_t)s1 * NOUT + c];
        acc = fmaf(dn * dinv[s0], h0, acc);
        acc = fmaf(dn * dinv[s1], h1v, acc);
    }
    if (e < end) {
        int s0 = csr_src[e];
        acc = fmaf(dn * dinv[s0], H[(size_t)s0 * NOUT + c], acc);
    }

    if (RELU) acc = fmaxf(acc, 0.f);
    out[(size_t)node * NOUT + c] = acc;
}

// ---------------- launch ----------------

extern "C" void kernel_launch(void* const* d_in, const int* in_sizes, int n_in,
                              void* d_out, int out_size, void* d_ws, size_t ws_size,
                              hipStream_t stream) {
    const float* x  = (const float*)d_in[0];
    const int*   ei = (const int*)d_in[1];   // [2, N_EDGES] int32
    const float* W1 = (const float*)d_in[2];
    const float* b1 = (const float*)d_in[3];
    const float* W2 = (const float*)d_in[4];
    const float* b2 = (const float*)d_in[5];

    const int* src = ei;
    const int* dst = ei + N_EDGES;

    // workspace layout (floats/ints are 4B; h1 at offset 0 keeps float4 alignment)
    float* h1     = (float*)d_ws;                       // 6,400,000 f
    float* h2     = h1 + (size_t)N_NODES * HID_C;       // 6,400,000 f
    float* dinv   = h2 + (size_t)N_NODES * HID_C;       // 50,048 f (padded)
    int*   degi   = (int*)(dinv + 50048);               // 50,048 i (reused as cursor)
    int*   rowptr = degi + 50048;                       // 50,001 i
    int*   csr    = rowptr + 50051;                     // 500,000 i
    float* h3     = h1;                                 // reuse h1 (3.2M f needed)

    float* out = (float*)d_out;

    // --- CSR build ---
    hipMemsetAsync(degi, 0, N_NODES * sizeof(int), stream);
    deg_kernel<<<(N_EDGES + 255) / 256, 256, 0, stream>>>(dst, degi);
    scan_kernel<<<1, 256, 0, stream>>>(degi, rowptr, dinv);
    // cursor := rowptr (reuse degi buffer as cursor)
    hipMemcpyAsync(degi, rowptr, N_NODES * sizeof(int), hipMemcpyDeviceToDevice, stream);
    fill_kernel<<<(N_EDGES + 255) / 256, 256, 0, stream>>>(src, dst, degi, csr);

    // --- layer 1 ---
    gemm_kernel<HID_C><<<(N_NODES + 31) / 32, 256, 0, stream>>>(x, W1, h1, N_NODES);
    agg_kernel<HID_C, true><<<(N_NODES + 1) / 2, 256, 0, stream>>>(rowptr, csr, dinv, h1, b1, h2);

    // --- layer 2 ---
    gemm_kernel<OUT_C><<<(N_NODES + 31) / 32, 256, 0, stream>>>(h2, W2, h3, N_NODES);
    agg_kernel<OUT_C, false><<<(N_NODES + 3) / 4, 256, 0, stream>>>(rowptr, csr, dinv, h3, b2, out);
}

// Round 3
// 233.217 us; speedup vs baseline: 6.0138x; 1.4801x over previous
//
#include <hip/hip_runtime.h>

#define N_NODES 50000
#define N_EDGES 500000
#define IN_C 128
#define HID_C 128
#define OUT_C 64

#define SCAN_NB ((N_NODES + 255) / 256)  // 196 blocks

// ---------------- CSR build ----------------

__global__ void deg_kernel(const int* __restrict__ dst, int* __restrict__ degi) {
    int e = blockIdx.x * blockDim.x + threadIdx.x;
    if (e < N_EDGES) atomicAdd(&degi[dst[e]], 1);
}

// scan1: per-block inclusive prefix of degi -> rowptr (in place), block sums, dinv
__global__ __launch_bounds__(256) void scan1_kernel(const int* __restrict__ degi,
                                                    int* __restrict__ rowptr,
                                                    int* __restrict__ blocksum,
                                                    float* __restrict__ dinv) {
    __shared__ int sh[256];
    const int t = threadIdx.x;
    const int i = blockIdx.x * 256 + t;
    int v = (i < N_NODES) ? degi[i] : 0;
    sh[t] = v;
    __syncthreads();
#pragma unroll
    for (int off = 1; off < 256; off <<= 1) {
        int tmp = (t >= off) ? sh[t - off] : 0;
        __syncthreads();
        sh[t] += tmp;
        __syncthreads();
    }
    if (i < N_NODES) {
        rowptr[i] = sh[t];  // inclusive within block, fixed up by scan3
        dinv[i] = rsqrtf((float)v + 1.0f);
    }
    if (t == 255) blocksum[blockIdx.x] = sh[255];
}

// scan2: exclusive scan of SCAN_NB (<=256) block sums, single block
__global__ __launch_bounds__(256) void scan2_kernel(int* __restrict__ blocksum) {
    __shared__ int sh[256];
    const int t = threadIdx.x;
    int v = (t < SCAN_NB) ? blocksum[t] : 0;
    sh[t] = v;
    __syncthreads();
#pragma unroll
    for (int off = 1; off < 256; off <<= 1) {
        int tmp = (t >= off) ? sh[t - off] : 0;
        __syncthreads();
        sh[t] += tmp;
        __syncthreads();
    }
    if (t < SCAN_NB) blocksum[t] = sh[t] - v;  // exclusive
}

// scan3: global exclusive rowptr; cursor (aliases degi) := rowptr
__global__ __launch_bounds__(256) void scan3_kernel(int* __restrict__ rowptr,
                                                    int* __restrict__ degi,
                                                    const int* __restrict__ blocksum) {
    const int i = blockIdx.x * 256 + threadIdx.x;
    if (i < N_NODES) {
        int d = degi[i];
        int ex = rowptr[i] - d + blocksum[blockIdx.x];
        rowptr[i] = ex;
        degi[i] = ex;  // cursor for fill
    }
    if (i == 0) rowptr[N_NODES] = N_EDGES;
}

__global__ void fill_kernel(const int* __restrict__ src, const int* __restrict__ dst,
                            int* __restrict__ cursor, int* __restrict__ csr_src) {
    int e = blockIdx.x * blockDim.x + threadIdx.x;
    if (e < N_EDGES) {
        int d = dst[e];
        int pos = atomicAdd(&cursor[d], 1);
        csr_src[pos] = src[e];
    }
}

// ---------------- GEMM: H[n, NOUT] = X[n, 128] @ W[128, NOUT] ----------------

template <int NOUT>
__global__ __launch_bounds__(256) void gemm_kernel(const float* __restrict__ X,
                                                   const float* __restrict__ W,
                                                   float* __restrict__ H, int nrows) {
    constexpr int ROWS = 32;
    constexpr int GROUPS = 256 / NOUT;   // 2 for NOUT=128, 4 for NOUT=64
    constexpr int RPT = ROWS / GROUPS;   // 16 or 8 rows per thread

    __shared__ float4 Xl[ROWS][32];      // 32 rows x 128 floats

    const int tx = threadIdx.x % NOUT;
    const int ty = threadIdx.x / NOUT;
    const int row0 = blockIdx.x * ROWS;

    for (int i = threadIdx.x; i < ROWS * 32; i += 256) {
        int r = i / 32, c = i % 32;
        int gr = row0 + r;
        Xl[r][c] = (gr < nrows) ? ((const float4*)X)[gr * 32 + c]
                                : make_float4(0.f, 0.f, 0.f, 0.f);
    }
    __syncthreads();

    float acc[RPT];
#pragma unroll
    for (int r = 0; r < RPT; r++) acc[r] = 0.f;

#pragma unroll 4
    for (int k4 = 0; k4 < 32; k4++) {
        const float w0 = W[(4 * k4 + 0) * NOUT + tx];
        const float w1 = W[(4 * k4 + 1) * NOUT + tx];
        const float w2 = W[(4 * k4 + 2) * NOUT + tx];
        const float w3 = W[(4 * k4 + 3) * NOUT + tx];
#pragma unroll
        for (int r = 0; r < RPT; r++) {
            float4 xv = Xl[ty * RPT + r][k4];
            acc[r] = fmaf(xv.x, w0, acc[r]);
            acc[r] = fmaf(xv.y, w1, acc[r]);
            acc[r] = fmaf(xv.z, w2, acc[r]);
            acc[r] = fmaf(xv.w, w3, acc[r]);
        }
    }

#pragma unroll
    for (int r = 0; r < RPT; r++) {
        int gr = row0 + ty * RPT + r;
        if (gr < nrows) H[gr * NOUT + tx] = acc[r];
    }
}

// ---------------- fused aggregation + epilogue ----------------
// out[n][c] = (relu?)( dinv[n]^2 * H[n][c] + b[c] + sum_{s in nbrs(n)} dinv[n]*dinv[s]*H[s][c] )

template <int NOUT, bool RELU>
__global__ __launch_bounds__(256) void agg_kernel(const int* __restrict__ rowptr,
                                                  const int* __restrict__ csr_src,
                                                  const float* __restrict__ dinv,
                                                  const float* __restrict__ H,
                                                  const float* __restrict__ b,
                                                  float* __restrict__ out) {
    constexpr int NPB = 256 / NOUT;  // nodes per block
    const int node = blockIdx.x * NPB + threadIdx.x / NOUT;
    const int c = threadIdx.x % NOUT;
    if (node >= N_NODES) return;

    const float dn = dinv[node];
    float acc = dn * dn * H[(size_t)node * NOUT + c] + b[c];

    int e = rowptr[node];
    const int end = rowptr[node + 1];

    for (; e + 1 < end; e += 2) {
        int s0 = csr_src[e];
        int s1 = csr_src[e + 1];
        float h0 = H[(size_t)s0 * NOUT + c];
        float h1v = H[(size_t)s1 * NOUT + c];
        acc = fmaf(dn * dinv[s0], h0, acc);
        acc = fmaf(dn * dinv[s1], h1v, acc);
    }
    if (e < end) {
        int s0 = csr_src[e];
        acc = fmaf(dn * dinv[s0], H[(size_t)s0 * NOUT + c], acc);
    }

    if (RELU) acc = fmaxf(acc, 0.f);
    out[(size_t)node * NOUT + c] = acc;
}

// ---------------- launch ----------------

extern "C" void kernel_launch(void* const* d_in, const int* in_sizes, int n_in,
                              void* d_out, int out_size, void* d_ws, size_t ws_size,
                              hipStream_t stream) {
    const float* x  = (const float*)d_in[0];
    const int*   ei = (const int*)d_in[1];   // [2, N_EDGES] int32
    const float* W1 = (const float*)d_in[2];
    const float* b1 = (const float*)d_in[3];
    const float* W2 = (const float*)d_in[4];
    const float* b2 = (const float*)d_in[5];

    const int* src = ei;
    const int* dst = ei + N_EDGES;

    // workspace layout
    float* h1     = (float*)d_ws;                        // 6,400,000 f
    float* h2     = h1 + (size_t)N_NODES * HID_C;        // 6,400,000 f
    float* dinv   = h2 + (size_t)N_NODES * HID_C;        // 50,048 f
    int*   degi   = (int*)(dinv + 50048);                // 50,048 i (becomes cursor)
    int*   rowptr = degi + 50048;                        // 50,001 i
    int*   csr    = rowptr + 50051;                      // 500,000 i
    int*   bsum   = csr + 500000;                        // 256 i
    float* h3     = h1;                                  // reuse h1

    float* out = (float*)d_out;

    // --- CSR build ---
    hipMemsetAsync(degi, 0, N_NODES * sizeof(int), stream);
    deg_kernel<<<(N_EDGES + 255) / 256, 256, 0, stream>>>(dst, degi);
    scan1_kernel<<<SCAN_NB, 256, 0, stream>>>(degi, rowptr, bsum, dinv);
    scan2_kernel<<<1, 256, 0, stream>>>(bsum);
    scan3_kernel<<<SCAN_NB, 256, 0, stream>>>(rowptr, degi, bsum);
    fill_kernel<<<(N_EDGES + 255) / 256, 256, 0, stream>>>(src, dst, degi, csr);

    // --- layer 1 ---
    gemm_kernel<HID_C><<<(N_NODES + 31) / 32, 256, 0, stream>>>(x, W1, h1, N_NODES);
    agg_kernel<HID_C, true><<<(N_NODES + 1) / 2, 256, 0, stream>>>(rowptr, csr, dinv, h1, b1, h2);

    // --- layer 2 ---
    gemm_kernel<OUT_C><<<(N_NODES + 31) / 32, 256, 0, stream>>>(h2, W2, h3, N_NODES);
    agg_kernel<OUT_C, false><<<(N_NODES + 3) / 4, 256, 0, stream>>>(rowptr, csr, dinv, h3, b2, out);
}

// Round 4
// 145.425 us; speedup vs baseline: 9.6443x; 1.6037x over previous
//
#include <hip/hip_runtime.h>

#define N_NODES 50000
#define N_EDGES 500000
#define IN_C 128
#define HID_C 128
#define OUT_C 64

#define SCAN_NB ((N_NODES + 255) / 256)  // 196 blocks

typedef short s16x8 __attribute__((ext_vector_type(8)));
typedef float f32x4 __attribute__((ext_vector_type(4)));

__device__ __forceinline__ unsigned short f2bf(float f) {
    unsigned int u = __float_as_uint(f);
    u = (u + 0x7FFF + ((u >> 16) & 1)) >> 16;  // round-to-nearest-even
    return (unsigned short)u;
}
__device__ __forceinline__ float bf2f(unsigned short u) {
    return __uint_as_float(((unsigned int)u) << 16);
}

// ---------------- CSR build ----------------

__global__ void deg_kernel(const int* __restrict__ dst, int* __restrict__ degi) {
    int e = blockIdx.x * blockDim.x + threadIdx.x;
    if (e < N_EDGES) atomicAdd(&degi[dst[e]], 1);
}

__global__ __launch_bounds__(256) void scan1_kernel(const int* __restrict__ degi,
                                                    int* __restrict__ rowptr,
                                                    int* __restrict__ blocksum,
                                                    float* __restrict__ dinv) {
    __shared__ int sh[256];
    const int t = threadIdx.x;
    const int i = blockIdx.x * 256 + t;
    int v = (i < N_NODES) ? degi[i] : 0;
    sh[t] = v;
    __syncthreads();
#pragma unroll
    for (int off = 1; off < 256; off <<= 1) {
        int tmp = (t >= off) ? sh[t - off] : 0;
        __syncthreads();
        sh[t] += tmp;
        __syncthreads();
    }
    if (i < N_NODES) {
        rowptr[i] = sh[t];
        dinv[i] = rsqrtf((float)v + 1.0f);
    }
    if (t == 255) blocksum[blockIdx.x] = sh[255];
}

__global__ __launch_bounds__(256) void scan2_kernel(int* __restrict__ blocksum) {
    __shared__ int sh[256];
    const int t = threadIdx.x;
    int v = (t < SCAN_NB) ? blocksum[t] : 0;
    sh[t] = v;
    __syncthreads();
#pragma unroll
    for (int off = 1; off < 256; off <<= 1) {
        int tmp = (t >= off) ? sh[t - off] : 0;
        __syncthreads();
        sh[t] += tmp;
        __syncthreads();
    }
    if (t < SCAN_NB) blocksum[t] = sh[t] - v;
}

__global__ __launch_bounds__(256) void scan3_kernel(int* __restrict__ rowptr,
                                                    int* __restrict__ degi,
                                                    const int* __restrict__ blocksum) {
    const int i = blockIdx.x * 256 + threadIdx.x;
    if (i < N_NODES) {
        int d = degi[i];
        int ex = rowptr[i] - d + blocksum[blockIdx.x];
        rowptr[i] = ex;
        degi[i] = ex;  // cursor for fill
    }
    if (i == 0) rowptr[N_NODES] = N_EDGES;
}

__global__ void fill_kernel(const int* __restrict__ src, const int* __restrict__ dst,
                            int* __restrict__ cursor, int* __restrict__ csr_src) {
    int e = blockIdx.x * blockDim.x + threadIdx.x;
    if (e < N_EDGES) {
        int d = dst[e];
        int pos = atomicAdd(&cursor[d], 1);
        csr_src[pos] = src[e];
    }
}

// ---------------- MFMA GEMM: H[n, NOUT](bf16) = X[n, 128] @ W[128, NOUT] ----------------
// 256 threads = 4 waves; 64 rows/block; wave w owns NT=NOUT/64 n-tiles.
// A/B fragment layout (mfma_f32_16x16x32_bf16):
//   A[j] = A[lane&15][(lane>>4)*8 + j],  B[j] = B[(lane>>4)*8 + j][lane&15]
//   C: col = lane&15, row = (lane>>4)*4 + reg   [m89-verified]

template <int NOUT, bool XBF16>
__global__ __launch_bounds__(256) void mfma_gemm(const void* __restrict__ Xv,
                                                 const float* __restrict__ W,
                                                 unsigned short* __restrict__ H, int nrows) {
    constexpr int NT = NOUT / 64;       // n-tiles per wave (2 for 128, 1 for 64)
    constexpr int SP = 136;             // padded LDS row stride (shorts)
    __shared__ unsigned short Xl[64 * SP];

    const int tid = threadIdx.x;
    const int w = tid >> 6;
    const int lane = tid & 63;
    const int kk = lane >> 4;           // 0..3
    const int cl = lane & 15;
    const int row0 = blockIdx.x * 64;

    // stage X tile (64 rows x 128 ch) as bf16 into LDS
    for (int c = tid; c < 64 * 32; c += 256) {
        int r = c >> 5, cc = c & 31;
        int gr = row0 + r;
        ushort4 o;
        if (XBF16) {
            o = (gr < nrows) ? ((const ushort4*)Xv)[(size_t)gr * 32 + cc]
                             : make_ushort4(0, 0, 0, 0);
        } else {
            if (gr < nrows) {
                float4 v = ((const float4*)Xv)[(size_t)gr * 32 + cc];
                o = make_ushort4(f2bf(v.x), f2bf(v.y), f2bf(v.z), f2bf(v.w));
            } else {
                o = make_ushort4(0, 0, 0, 0);
            }
        }
        *(ushort4*)&Xl[r * SP + cc * 4] = o;
    }

    // B fragments from global W (f32 -> bf16), held in registers
    s16x8 bfrag[NT][4];
#pragma unroll
    for (int i = 0; i < NT; i++) {
        int colg = (w * NT + i) * 16 + cl;
#pragma unroll
        for (int s = 0; s < 4; s++) {
#pragma unroll
            for (int j = 0; j < 8; j++) {
                int k = s * 32 + kk * 8 + j;
                bfrag[i][s][j] = (short)f2bf(W[k * NOUT + colg]);
            }
        }
    }

    __syncthreads();

    f32x4 acc[4][NT];
#pragma unroll
    for (int rt = 0; rt < 4; rt++)
#pragma unroll
        for (int i = 0; i < NT; i++) acc[rt][i] = (f32x4){0.f, 0.f, 0.f, 0.f};

#pragma unroll
    for (int rt = 0; rt < 4; rt++) {
        const int rl = rt * 16 + cl;
        s16x8 a[4];
#pragma unroll
        for (int s = 0; s < 4; s++)
            a[s] = *(const s16x8*)&Xl[rl * SP + s * 32 + kk * 8];
#pragma unroll
        for (int i = 0; i < NT; i++)
#pragma unroll
            for (int s = 0; s < 4; s++)
                acc[rt][i] = __builtin_amdgcn_mfma_f32_16x16x32_bf16(a[s], bfrag[i][s],
                                                                     acc[rt][i], 0, 0, 0);
    }

#pragma unroll
    for (int rt = 0; rt < 4; rt++) {
#pragma unroll
        for (int i = 0; i < NT; i++) {
            int colg = (w * NT + i) * 16 + cl;
#pragma unroll
            for (int r = 0; r < 4; r++) {
                int rowg = row0 + rt * 16 + kk * 4 + r;
                if (rowg < nrows) H[(size_t)rowg * NOUT + colg] = f2bf(acc[rt][i][r]);
            }
        }
    }
}

// ---------------- fused aggregation + epilogue (bf16 H) ----------------
// out[n][c] = (relu?)( dinv[n]^2 * H[n][c] + b[c] + sum_{s in nbrs(n)} dinv[n]*dinv[s]*H[s][c] )
// LANES = NOUT/2 lanes per node, each lane handles a packed bf16x2 (u32).

template <int NOUT, bool RELU, bool OUTF32>
__global__ __launch_bounds__(256) void agg_kernel(const int* __restrict__ rowptr,
                                                  const int* __restrict__ csr_src,
                                                  const float* __restrict__ dinv,
                                                  const unsigned int* __restrict__ H,  // bf16x2
                                                  const float* __restrict__ b,
                                                  void* __restrict__ outv) {
    constexpr int LANES = NOUT / 2;
    constexpr int NPB = 256 / LANES;
    const int node = blockIdx.x * NPB + threadIdx.x / LANES;
    const int c2 = threadIdx.x % LANES;
    if (node >= N_NODES) return;

    const float dn = dinv[node];
    const unsigned int hv0 = H[(size_t)node * LANES + c2];
    float acc0 = dn * dn * bf2f((unsigned short)(hv0 & 0xffff)) + b[2 * c2];
    float acc1 = dn * dn * bf2f((unsigned short)(hv0 >> 16)) + b[2 * c2 + 1];

    int e = rowptr[node];
    const int end = rowptr[node + 1];

    for (; e + 1 < end; e += 2) {
        int s0 = csr_src[e];
        int s1 = csr_src[e + 1];
        float c0 = dn * dinv[s0];
        float c1 = dn * dinv[s1];
        unsigned int h0 = H[(size_t)s0 * LANES + c2];
        unsigned int h1 = H[(size_t)s1 * LANES + c2];
        acc0 = fmaf(c0, bf2f((unsigned short)(h0 & 0xffff)), acc0);
        acc1 = fmaf(c0, bf2f((unsigned short)(h0 >> 16)), acc1);
        acc0 = fmaf(c1, bf2f((unsigned short)(h1 & 0xffff)), acc0);
        acc1 = fmaf(c1, bf2f((unsigned short)(h1 >> 16)), acc1);
    }
    if (e < end) {
        int s0 = csr_src[e];
        float c0 = dn * dinv[s0];
        unsigned int h0 = H[(size_t)s0 * LANES + c2];
        acc0 = fmaf(c0, bf2f((unsigned short)(h0 & 0xffff)), acc0);
        acc1 = fmaf(c0, bf2f((unsigned short)(h0 >> 16)), acc1);
    }

    if (RELU) {
        acc0 = fmaxf(acc0, 0.f);
        acc1 = fmaxf(acc1, 0.f);
    }
    if (OUTF32) {
        float2* out = (float2*)outv;
        out[(size_t)node * LANES + c2] = make_float2(acc0, acc1);
    } else {
        unsigned int* out = (unsigned int*)outv;
        out[(size_t)node * LANES + c2] =
            (unsigned int)f2bf(acc0) | ((unsigned int)f2bf(acc1) << 16);
    }
}

// ---------------- launch ----------------

extern "C" void kernel_launch(void* const* d_in, const int* in_sizes, int n_in,
                              void* d_out, int out_size, void* d_ws, size_t ws_size,
                              hipStream_t stream) {
    const float* x  = (const float*)d_in[0];
    const int*   ei = (const int*)d_in[1];
    const float* W1 = (const float*)d_in[2];
    const float* b1 = (const float*)d_in[3];
    const float* W2 = (const float*)d_in[4];
    const float* b2 = (const float*)d_in[5];

    const int* src = ei;
    const int* dst = ei + N_EDGES;

    // workspace layout
    unsigned short* h1 = (unsigned short*)d_ws;                 // 6.4M bf16
    unsigned short* h2 = h1 + (size_t)N_NODES * HID_C;          // 6.4M bf16
    float* dinv  = (float*)(h2 + (size_t)N_NODES * HID_C);      // 50,048 f
    int*   degi  = (int*)(dinv + 50048);                        // 50,048 i (cursor)
    int*   rowptr = degi + 50048;                               // 50,001 i
    int*   csr   = rowptr + 50051;                              // 500,000 i
    int*   bsum  = csr + 500000;                                // 256 i
    unsigned short* h3 = h1;                                    // reuse h1 (3.2M bf16)

    // --- CSR build ---
    hipMemsetAsync(degi, 0, N_NODES * sizeof(int), stream);
    deg_kernel<<<(N_EDGES + 255) / 256, 256, 0, stream>>>(dst, degi);
    scan1_kernel<<<SCAN_NB, 256, 0, stream>>>(degi, rowptr, bsum, dinv);
    scan2_kernel<<<1, 256, 0, stream>>>(bsum);
    scan3_kernel<<<SCAN_NB, 256, 0, stream>>>(rowptr, degi, bsum);
    fill_kernel<<<(N_EDGES + 255) / 256, 256, 0, stream>>>(src, dst, degi, csr);

    const int gemm_grid = (N_NODES + 63) / 64;

    // --- layer 1 ---
    mfma_gemm<HID_C, false><<<gemm_grid, 256, 0, stream>>>(x, W1, h1, N_NODES);
    agg_kernel<HID_C, true, false><<<(N_NODES + 3) / 4, 256, 0, stream>>>(
        rowptr, csr, dinv, (const unsigned int*)h1, b1, h2);

    // --- layer 2 ---
    mfma_gemm<OUT_C, true><<<gemm_grid, 256, 0, stream>>>(h2, W2, h3, N_NODES);
    agg_kernel<OUT_C, false, true><<<(N_NODES + 7) / 8, 256, 0, stream>>>(
        rowptr, csr, dinv, (const unsigned int*)h3, b2, d_out);
}

// Round 5
// 145.147 us; speedup vs baseline: 9.6628x; 1.0019x over previous
//
#include <hip/hip_runtime.h>

#define N_NODES 50000
#define N_EDGES 500000
#define IN_C 128
#define HID_C 128
#define OUT_C 64

#define SCAN_NB ((N_NODES + 255) / 256)  // 196 blocks

typedef short s16x8 __attribute__((ext_vector_type(8)));
typedef float f32x4 __attribute__((ext_vector_type(4)));

__device__ __forceinline__ unsigned short f2bf(float f) {
    unsigned int u = __float_as_uint(f);
    u = (u + 0x7FFF + ((u >> 16) & 1)) >> 16;  // round-to-nearest-even
    return (unsigned short)u;
}
__device__ __forceinline__ float bf2f(unsigned short u) {
    return __uint_as_float(((unsigned int)u) << 16);
}

// ---------------- zero (replaces pathological rocclr fillBuffer, 43us -> ~2us) ----------------

__global__ __launch_bounds__(256) void zero_kernel(int4* __restrict__ p, int n4) {
    int i = blockIdx.x * blockDim.x + threadIdx.x;
    if (i < n4) p[i] = make_int4(0, 0, 0, 0);
}

// ---------------- CSR build ----------------

__global__ void deg_kernel(const int* __restrict__ dst, int* __restrict__ degi) {
    int e = blockIdx.x * blockDim.x + threadIdx.x;
    if (e < N_EDGES) atomicAdd(&degi[dst[e]], 1);
}

__global__ __launch_bounds__(256) void scan1_kernel(const int* __restrict__ degi,
                                                    int* __restrict__ rowptr,
                                                    int* __restrict__ blocksum,
                                                    float* __restrict__ dinv) {
    __shared__ int sh[256];
    const int t = threadIdx.x;
    const int i = blockIdx.x * 256 + t;
    int v = (i < N_NODES) ? degi[i] : 0;
    sh[t] = v;
    __syncthreads();
#pragma unroll
    for (int off = 1; off < 256; off <<= 1) {
        int tmp = (t >= off) ? sh[t - off] : 0;
        __syncthreads();
        sh[t] += tmp;
        __syncthreads();
    }
    if (i < N_NODES) {
        rowptr[i] = sh[t];
        dinv[i] = rsqrtf((float)v + 1.0f);
    }
    if (t == 255) blocksum[blockIdx.x] = sh[255];
}

__global__ __launch_bounds__(256) void scan2_kernel(int* __restrict__ blocksum) {
    __shared__ int sh[256];
    const int t = threadIdx.x;
    int v = (t < SCAN_NB) ? blocksum[t] : 0;
    sh[t] = v;
    __syncthreads();
#pragma unroll
    for (int off = 1; off < 256; off <<= 1) {
        int tmp = (t >= off) ? sh[t - off] : 0;
        __syncthreads();
        sh[t] += tmp;
        __syncthreads();
    }
    if (t < SCAN_NB) blocksum[t] = sh[t] - v;
}

__global__ __launch_bounds__(256) void scan3_kernel(int* __restrict__ rowptr,
                                                    int* __restrict__ degi,
                                                    const int* __restrict__ blocksum) {
    const int i = blockIdx.x * 256 + threadIdx.x;
    if (i < N_NODES) {
        int d = degi[i];
        int ex = rowptr[i] - d + blocksum[blockIdx.x];
        rowptr[i] = ex;
        degi[i] = ex;  // cursor for fill
    }
    if (i == 0) rowptr[N_NODES] = N_EDGES;
}

__global__ void fill_kernel(const int* __restrict__ src, const int* __restrict__ dst,
                            int* __restrict__ cursor, int* __restrict__ csr_src) {
    int e = blockIdx.x * blockDim.x + threadIdx.x;
    if (e < N_EDGES) {
        int d = dst[e];
        int pos = atomicAdd(&cursor[d], 1);
        csr_src[pos] = src[e];
    }
}

// ---------------- MFMA GEMM: H[n, NOUT](bf16) = X[n, 128] @ W[128, NOUT] ----------------

template <int NOUT, bool XBF16>
__global__ __launch_bounds__(256) void mfma_gemm(const void* __restrict__ Xv,
                                                 const float* __restrict__ W,
                                                 unsigned short* __restrict__ H, int nrows) {
    constexpr int NT = NOUT / 64;       // n-tiles per wave (2 for 128, 1 for 64)
    constexpr int SP = 136;             // padded LDS row stride (shorts)
    __shared__ unsigned short Xl[64 * SP];

    const int tid = threadIdx.x;
    const int w = tid >> 6;
    const int lane = tid & 63;
    const int kk = lane >> 4;           // 0..3
    const int cl = lane & 15;
    const int row0 = blockIdx.x * 64;

    for (int c = tid; c < 64 * 32; c += 256) {
        int r = c >> 5, cc = c & 31;
        int gr = row0 + r;
        ushort4 o;
        if (XBF16) {
            o = (gr < nrows) ? ((const ushort4*)Xv)[(size_t)gr * 32 + cc]
                             : make_ushort4(0, 0, 0, 0);
        } else {
            if (gr < nrows) {
                float4 v = ((const float4*)Xv)[(size_t)gr * 32 + cc];
                o = make_ushort4(f2bf(v.x), f2bf(v.y), f2bf(v.z), f2bf(v.w));
            } else {
                o = make_ushort4(0, 0, 0, 0);
            }
        }
        *(ushort4*)&Xl[r * SP + cc * 4] = o;
    }

    s16x8 bfrag[NT][4];
#pragma unroll
    for (int i = 0; i < NT; i++) {
        int colg = (w * NT + i) * 16 + cl;
#pragma unroll
        for (int s = 0; s < 4; s++) {
#pragma unroll
            for (int j = 0; j < 8; j++) {
                int k = s * 32 + kk * 8 + j;
                bfrag[i][s][j] = (short)f2bf(W[k * NOUT + colg]);
            }
        }
    }

    __syncthreads();

    f32x4 acc[4][NT];
#pragma unroll
    for (int rt = 0; rt < 4; rt++)
#pragma unroll
        for (int i = 0; i < NT; i++) acc[rt][i] = (f32x4){0.f, 0.f, 0.f, 0.f};

#pragma unroll
    for (int rt = 0; rt < 4; rt++) {
        const int rl = rt * 16 + cl;
        s16x8 a[4];
#pragma unroll
        for (int s = 0; s < 4; s++)
            a[s] = *(const s16x8*)&Xl[rl * SP + s * 32 + kk * 8];
#pragma unroll
        for (int i = 0; i < NT; i++)
#pragma unroll
            for (int s = 0; s < 4; s++)
                acc[rt][i] = __builtin_amdgcn_mfma_f32_16x16x32_bf16(a[s], bfrag[i][s],
                                                                     acc[rt][i], 0, 0, 0);
    }

#pragma unroll
    for (int rt = 0; rt < 4; rt++) {
#pragma unroll
        for (int i = 0; i < NT; i++) {
            int colg = (w * NT + i) * 16 + cl;
#pragma unroll
            for (int r = 0; r < 4; r++) {
                int rowg = row0 + rt * 16 + kk * 4 + r;
                if (rowg < nrows) H[(size_t)rowg * NOUT + colg] = f2bf(acc[rt][i][r]);
            }
        }
    }
}

// ---------------- fused aggregation + epilogue (bf16 H) ----------------

template <int NOUT, bool RELU, bool OUTF32>
__global__ __launch_bounds__(256) void agg_kernel(const int* __restrict__ rowptr,
                                                  const int* __restrict__ csr_src,
                                                  const float* __restrict__ dinv,
                                                  const unsigned int* __restrict__ H,  // bf16x2
                                                  const float* __restrict__ b,
                                                  void* __restrict__ outv) {
    constexpr int LANES = NOUT / 2;
    constexpr int NPB = 256 / LANES;
    const int node = blockIdx.x * NPB + threadIdx.x / LANES;
    const int c2 = threadIdx.x % LANES;
    if (node >= N_NODES) return;

    const float dn = dinv[node];
    const unsigned int hv0 = H[(size_t)node * LANES + c2];
    float acc0 = dn * dn * bf2f((unsigned short)(hv0 & 0xffff)) + b[2 * c2];
    float acc1 = dn * dn * bf2f((unsigned short)(hv0 >> 16)) + b[2 * c2 + 1];

    int e = rowptr[node];
    const int end = rowptr[node + 1];

    for (; e + 1 < end; e += 2) {
        int s0 = csr_src[e];
        int s1 = csr_src[e + 1];
        float c0 = dn * dinv[s0];
        float c1 = dn * dinv[s1];
        unsigned int h0 = H[(size_t)s0 * LANES + c2];
        unsigned int h1 = H[(size_t)s1 * LANES + c2];
        acc0 = fmaf(c0, bf2f((unsigned short)(h0 & 0xffff)), acc0);
        acc1 = fmaf(c0, bf2f((unsigned short)(h0 >> 16)), acc1);
        acc0 = fmaf(c1, bf2f((unsigned short)(h1 & 0xffff)), acc0);
        acc1 = fmaf(c1, bf2f((unsigned short)(h1 >> 16)), acc1);
    }
    if (e < end) {
        int s0 = csr_src[e];
        float c0 = dn * dinv[s0];
        unsigned int h0 = H[(size_t)s0 * LANES + c2];
        acc0 = fmaf(c0, bf2f((unsigned short)(h0 & 0xffff)), acc0);
        acc1 = fmaf(c0, bf2f((unsigned short)(h0 >> 16)), acc1);
    }

    if (RELU) {
        acc0 = fmaxf(acc0, 0.f);
        acc1 = fmaxf(acc1, 0.f);
    }
    if (OUTF32) {
        float2* out = (float2*)outv;
        out[(size_t)node * LANES + c2] = make_float2(acc0, acc1);
    } else {
        unsigned int* out = (unsigned int*)outv;
        out[(size_t)node * LANES + c2] =
            (unsigned int)f2bf(acc0) | ((unsigned int)f2bf(acc1) << 16);
    }
}

// ---------------- launch ----------------

extern "C" void kernel_launch(void* const* d_in, const int* in_sizes, int n_in,
                              void* d_out, int out_size, void* d_ws, size_t ws_size,
                              hipStream_t stream) {
    const float* x  = (const float*)d_in[0];
    const int*   ei = (const int*)d_in[1];
    const float* W1 = (const float*)d_in[2];
    const float* b1 = (const float*)d_in[3];
    const float* W2 = (const float*)d_in[4];
    const float* b2 = (const float*)d_in[5];

    const int* src = ei;
    const int* dst = ei + N_EDGES;

    // workspace layout
    unsigned short* h1 = (unsigned short*)d_ws;                 // 6.4M bf16
    unsigned short* h2 = h1 + (size_t)N_NODES * HID_C;          // 6.4M bf16
    float* dinv  = (float*)(h2 + (size_t)N_NODES * HID_C);      // 50,048 f
    int*   degi  = (int*)(dinv + 50048);                        // 50,048 i (cursor)
    int*   rowptr = degi + 50048;                               // 50,001 i
    int*   csr   = rowptr + 50051;                              // 500,000 i
    int*   bsum  = csr + 500000;                                // 256 i
    unsigned short* h3 = h1;                                    // reuse h1 (3.2M bf16)

    // --- CSR build ---
    {
        int n4 = (N_NODES + 3) / 4;  // 12500 int4s over degi
        zero_kernel<<<(n4 + 255) / 256, 256, 0, stream>>>((int4*)degi, n4);
    }
    deg_kernel<<<(N_EDGES + 255) / 256, 256, 0, stream>>>(dst, degi);
    scan1_kernel<<<SCAN_NB, 256, 0, stream>>>(degi, rowptr, bsum, dinv);
    scan2_kernel<<<1, 256, 0, stream>>>(bsum);
    scan3_kernel<<<SCAN_NB, 256, 0, stream>>>(rowptr, degi, bsum);
    fill_kernel<<<(N_EDGES + 255) / 256, 256, 0, stream>>>(src, dst, degi, csr);

    const int gemm_grid = (N_NODES + 63) / 64;

    // --- layer 1 ---
    mfma_gemm<HID_C, false><<<gemm_grid, 256, 0, stream>>>(x, W1, h1, N_NODES);
    agg_kernel<HID_C, true, false><<<(N_NODES + 3) / 4, 256, 0, stream>>>(
        rowptr, csr, dinv, (const unsigned int*)h1, b1, h2);

    // --- layer 2 ---
    mfma_gemm<OUT_C, true><<<gemm_grid, 256, 0, stream>>>(h2, W2, h3, N_NODES);
    agg_kernel<OUT_C, false, true><<<(N_NODES + 7) / 8, 256, 0, stream>>>(
        rowptr, csr, dinv, (const unsigned int*)h3, b2, d_out);
}

// Round 6
// 139.604 us; speedup vs baseline: 10.0464x; 1.0397x over previous
//
#include <hip/hip_runtime.h>

#define N_NODES 50000
#define N_EDGES 500000
#define IN_C 128
#define HID_C 128
#define OUT_C 64

#define SCAN_NB ((N_NODES + 255) / 256)  // 196 blocks

typedef short s16x8 __attribute__((ext_vector_type(8)));
typedef float f32x4 __attribute__((ext_vector_type(4)));

__device__ __forceinline__ unsigned short f2bf(float f) {
    unsigned int u = __float_as_uint(f);
    u = (u + 0x7FFF + ((u >> 16) & 1)) >> 16;  // round-to-nearest-even
    return (unsigned short)u;
}
__device__ __forceinline__ float bf2f(unsigned short u) {
    return __uint_as_float(((unsigned int)u) << 16);
}

// ---------------- zero ----------------

__global__ __launch_bounds__(256) void zero_kernel(int4* __restrict__ p, int n4) {
    int i = blockIdx.x * blockDim.x + threadIdx.x;
    if (i < n4) p[i] = make_int4(0, 0, 0, 0);
}

// ---------------- CSR build ----------------

__global__ void deg_kernel(const int* __restrict__ dst, int* __restrict__ degi) {
    int e = blockIdx.x * blockDim.x + threadIdx.x;
    if (e < N_EDGES) atomicAdd(&degi[dst[e]], 1);
}

__global__ __launch_bounds__(256) void scan1_kernel(const int* __restrict__ degi,
                                                    int* __restrict__ rowptr,
                                                    int* __restrict__ blocksum,
                                                    float* __restrict__ dinv) {
    __shared__ int sh[256];
    const int t = threadIdx.x;
    const int i = blockIdx.x * 256 + t;
    int v = (i < N_NODES) ? degi[i] : 0;
    sh[t] = v;
    __syncthreads();
#pragma unroll
    for (int off = 1; off < 256; off <<= 1) {
        int tmp = (t >= off) ? sh[t - off] : 0;
        __syncthreads();
        sh[t] += tmp;
        __syncthreads();
    }
    if (i < N_NODES) {
        rowptr[i] = sh[t];
        dinv[i] = rsqrtf((float)v + 1.0f);
    }
    if (t == 255) blocksum[blockIdx.x] = sh[255];
}

__global__ __launch_bounds__(256) void scan2_kernel(int* __restrict__ blocksum) {
    __shared__ int sh[256];
    const int t = threadIdx.x;
    int v = (t < SCAN_NB) ? blocksum[t] : 0;
    sh[t] = v;
    __syncthreads();
#pragma unroll
    for (int off = 1; off < 256; off <<= 1) {
        int tmp = (t >= off) ? sh[t - off] : 0;
        __syncthreads();
        sh[t] += tmp;
        __syncthreads();
    }
    if (t < SCAN_NB) blocksum[t] = sh[t] - v;
}

__global__ __launch_bounds__(256) void scan3_kernel(int* __restrict__ rowptr,
                                                    int* __restrict__ degi,
                                                    const int* __restrict__ blocksum) {
    const int i = blockIdx.x * 256 + threadIdx.x;
    if (i < N_NODES) {
        int d = degi[i];
        int ex = rowptr[i] - d + blocksum[blockIdx.x];
        rowptr[i] = ex;
        degi[i] = ex;  // cursor for fill
    }
    if (i == 0) rowptr[N_NODES] = N_EDGES;
}

__global__ void fill_kernel(const int* __restrict__ src, const int* __restrict__ dst,
                            int* __restrict__ cursor, int* __restrict__ csr_src) {
    int e = blockIdx.x * blockDim.x + threadIdx.x;
    if (e < N_EDGES) {
        int d = dst[e];
        int pos = atomicAdd(&cursor[d], 1);
        csr_src[pos] = src[e];
    }
}

// ---------------- MFMA GEMM: H[n, NOUT](bf16) = dinv[n] * (X[n, 128] @ W[128, NOUT]) ----------------
// Rows are PRE-SCALED by dinv so the agg gather needs no per-src dinv lookups:
// out[n] = dinv[n] * (h'[n] + sum_{s} h'[s]) + b,  h'[n] = dinv[n] * (x@W)[n].

template <int NOUT, bool XBF16>
__global__ __launch_bounds__(256) void mfma_gemm(const void* __restrict__ Xv,
                                                 const float* __restrict__ W,
                                                 const float* __restrict__ dinv,
                                                 unsigned short* __restrict__ H, int nrows) {
    constexpr int NT = NOUT / 64;       // n-tiles per wave (2 for 128, 1 for 64)
    constexpr int SP = 136;             // padded LDS row stride (shorts)
    __shared__ unsigned short Xl[64 * SP];

    const int tid = threadIdx.x;
    const int w = tid >> 6;
    const int lane = tid & 63;
    const int kk = lane >> 4;           // 0..3
    const int cl = lane & 15;
    const int row0 = blockIdx.x * 64;

    for (int c = tid; c < 64 * 32; c += 256) {
        int r = c >> 5, cc = c & 31;
        int gr = row0 + r;
        ushort4 o;
        if (XBF16) {
            o = (gr < nrows) ? ((const ushort4*)Xv)[(size_t)gr * 32 + cc]
                             : make_ushort4(0, 0, 0, 0);
        } else {
            if (gr < nrows) {
                float4 v = ((const float4*)Xv)[(size_t)gr * 32 + cc];
                o = make_ushort4(f2bf(v.x), f2bf(v.y), f2bf(v.z), f2bf(v.w));
            } else {
                o = make_ushort4(0, 0, 0, 0);
            }
        }
        *(ushort4*)&Xl[r * SP + cc * 4] = o;
    }

    s16x8 bfrag[NT][4];
#pragma unroll
    for (int i = 0; i < NT; i++) {
        int colg = (w * NT + i) * 16 + cl;
#pragma unroll
        for (int s = 0; s < 4; s++) {
#pragma unroll
            for (int j = 0; j < 8; j++) {
                int k = s * 32 + kk * 8 + j;
                bfrag[i][s][j] = (short)f2bf(W[k * NOUT + colg]);
            }
        }
    }

    __syncthreads();

    f32x4 acc[4][NT];
#pragma unroll
    for (int rt = 0; rt < 4; rt++)
#pragma unroll
        for (int i = 0; i < NT; i++) acc[rt][i] = (f32x4){0.f, 0.f, 0.f, 0.f};

#pragma unroll
    for (int rt = 0; rt < 4; rt++) {
        const int rl = rt * 16 + cl;
        s16x8 a[4];
#pragma unroll
        for (int s = 0; s < 4; s++)
            a[s] = *(const s16x8*)&Xl[rl * SP + s * 32 + kk * 8];
#pragma unroll
        for (int i = 0; i < NT; i++)
#pragma unroll
            for (int s = 0; s < 4; s++)
                acc[rt][i] = __builtin_amdgcn_mfma_f32_16x16x32_bf16(a[s], bfrag[i][s],
                                                                     acc[rt][i], 0, 0, 0);
    }

#pragma unroll
    for (int rt = 0; rt < 4; rt++) {
        // dinv for this wave's 4 rows (16B-aligned; padded region is never stored)
        float4 dv = *(const float4*)&dinv[row0 + rt * 16 + kk * 4];
        float dvv[4] = {dv.x, dv.y, dv.z, dv.w};
#pragma unroll
        for (int i = 0; i < NT; i++) {
            int colg = (w * NT + i) * 16 + cl;
#pragma unroll
            for (int r = 0; r < 4; r++) {
                int rowg = row0 + rt * 16 + kk * 4 + r;
                if (rowg < nrows) H[(size_t)rowg * NOUT + colg] = f2bf(dvv[r] * acc[rt][i][r]);
            }
        }
    }
}

// ---------------- fused aggregation + epilogue (pre-scaled bf16 H) ----------------
// out[n][c] = (relu?)( dinv[n] * (H'[n][c] + sum_{s in nbrs(n)} H'[s][c]) + b[c] )

template <int NOUT, bool RELU, bool OUTF32>
__global__ __launch_bounds__(256) void agg_kernel(const int* __restrict__ rowptr,
                                                  const int* __restrict__ csr_src,
                                                  const float* __restrict__ dinv,
                                                  const unsigned int* __restrict__ H,  // bf16x2
                                                  const float* __restrict__ b,
                                                  void* __restrict__ outv) {
    constexpr int LANES = NOUT / 2;
    constexpr int NPB = 256 / LANES;
    const int node = blockIdx.x * NPB + threadIdx.x / LANES;
    const int c2 = threadIdx.x % LANES;
    if (node >= N_NODES) return;

    float acc0, acc1;
    {
        unsigned int hv = H[(size_t)node * LANES + c2];
        acc0 = bf2f((unsigned short)(hv & 0xffff));
        acc1 = bf2f((unsigned short)(hv >> 16));
    }

    int e = rowptr[node];
    const int end = rowptr[node + 1];

    // 4-deep unroll: 4 independent row gathers in flight per wave
    for (; e + 3 < end; e += 4) {
        int s0 = csr_src[e];
        int s1 = csr_src[e + 1];
        int s2 = csr_src[e + 2];
        int s3 = csr_src[e + 3];
        unsigned int h0 = H[(size_t)s0 * LANES + c2];
        unsigned int h1 = H[(size_t)s1 * LANES + c2];
        unsigned int h2 = H[(size_t)s2 * LANES + c2];
        unsigned int h3 = H[(size_t)s3 * LANES + c2];
        acc0 += bf2f((unsigned short)(h0 & 0xffff));
        acc1 += bf2f((unsigned short)(h0 >> 16));
        acc0 += bf2f((unsigned short)(h1 & 0xffff));
        acc1 += bf2f((unsigned short)(h1 >> 16));
        acc0 += bf2f((unsigned short)(h2 & 0xffff));
        acc1 += bf2f((unsigned short)(h2 >> 16));
        acc0 += bf2f((unsigned short)(h3 & 0xffff));
        acc1 += bf2f((unsigned short)(h3 >> 16));
    }
    for (; e < end; e++) {
        int s0 = csr_src[e];
        unsigned int h0 = H[(size_t)s0 * LANES + c2];
        acc0 += bf2f((unsigned short)(h0 & 0xffff));
        acc1 += bf2f((unsigned short)(h0 >> 16));
    }

    const float dn = dinv[node];
    acc0 = fmaf(dn, acc0, b[2 * c2]);
    acc1 = fmaf(dn, acc1, b[2 * c2 + 1]);

    if (RELU) {
        acc0 = fmaxf(acc0, 0.f);
        acc1 = fmaxf(acc1, 0.f);
    }
    if (OUTF32) {
        float2* out = (float2*)outv;
        out[(size_t)node * LANES + c2] = make_float2(acc0, acc1);
    } else {
        unsigned int* out = (unsigned int*)outv;
        out[(size_t)node * LANES + c2] =
            (unsigned int)f2bf(acc0) | ((unsigned int)f2bf(acc1) << 16);
    }
}

// ---------------- launch ----------------

extern "C" void kernel_launch(void* const* d_in, const int* in_sizes, int n_in,
                              void* d_out, int out_size, void* d_ws, size_t ws_size,
                              hipStream_t stream) {
    const float* x  = (const float*)d_in[0];
    const int*   ei = (const int*)d_in[1];
    const float* W1 = (const float*)d_in[2];
    const float* b1 = (const float*)d_in[3];
    const float* W2 = (const float*)d_in[4];
    const float* b2 = (const float*)d_in[5];

    const int* src = ei;
    const int* dst = ei + N_EDGES;

    // workspace layout
    unsigned short* h1 = (unsigned short*)d_ws;                 // 6.4M bf16 (pre-scaled h')
    unsigned short* h2 = h1 + (size_t)N_NODES * HID_C;          // 6.4M bf16 (activations)
    float* dinv  = (float*)(h2 + (size_t)N_NODES * HID_C);      // 50,048 f
    int*   degi  = (int*)(dinv + 50048);                        // 50,048 i (cursor)
    int*   rowptr = degi + 50048;                               // 50,001 i
    int*   csr   = rowptr + 50051;                              // 500,000 i
    int*   bsum  = csr + 500000;                                // 256 i
    unsigned short* h3 = h1;                                    // reuse h1 (3.2M bf16)

    // --- CSR build ---
    {
        int n4 = (N_NODES + 3) / 4;
        zero_kernel<<<(n4 + 255) / 256, 256, 0, stream>>>((int4*)degi, n4);
    }
    deg_kernel<<<(N_EDGES + 255) / 256, 256, 0, stream>>>(dst, degi);
    scan1_kernel<<<SCAN_NB, 256, 0, stream>>>(degi, rowptr, bsum, dinv);
    scan2_kernel<<<1, 256, 0, stream>>>(bsum);
    scan3_kernel<<<SCAN_NB, 256, 0, stream>>>(rowptr, degi, bsum);
    fill_kernel<<<(N_EDGES + 255) / 256, 256, 0, stream>>>(src, dst, degi, csr);

    const int gemm_grid = (N_NODES + 63) / 64;

    // --- layer 1 ---
    mfma_gemm<HID_C, false><<<gemm_grid, 256, 0, stream>>>(x, W1, dinv, h1, N_NODES);
    agg_kernel<HID_C, true, false><<<(N_NODES + 3) / 4, 256, 0, stream>>>(
        rowptr, csr, dinv, (const unsigned int*)h1, b1, h2);

    // --- layer 2 ---
    mfma_gemm<OUT_C, true><<<gemm_grid, 256, 0, stream>>>(h2, W2, dinv, h3, N_NODES);
    agg_kernel<OUT_C, false, true><<<(N_NODES + 7) / 8, 256, 0, stream>>>(
        rowptr, csr, dinv, (const unsigned int*)h3, b2, d_out);
}